// Round 3
// baseline (448.998 us; speedup 1.0000x reference)
//
#include <hip/hip_runtime.h>

#define IN_FEATS 128
#define OUT_FEATS 64
#define TM 64              // rows per linear block
#define ALD 136            // bf16 LDS leading dim
#define BW_LOG 6           // bucket width = 64 nodes
#define BWIDTH 64
#define MAX_NB 1024
#define SE_PER_BLK 2048    // edges per stage block (256 thr x 8, single pass)
#define CAP 2048           // fixed records per bucket region (mean ~1023, max ~1140)
#define APAD 65            // acc tile leading pad: bank = (4*l4 + k + nl) % 32

typedef short bf16x8 __attribute__((ext_vector_type(8)));
typedef float f32x4 __attribute__((ext_vector_type(4)));

__device__ inline unsigned short f2bf(float f) {   // RTNE fp32 -> bf16
    unsigned u = __float_as_uint(f);
    u += 0x7FFFu + ((u >> 16) & 1u);
    return (unsigned short)(u >> 16);
}
__device__ inline float bf2f_lo(unsigned v) { return __uint_as_float(v << 16); }
__device__ inline float bf2f_hi(unsigned v) { return __uint_as_float(v & 0xFFFF0000u); }
__device__ inline ushort4 cvt4(float4 t) {
    ushort4 s; s.x = f2bf(t.x); s.y = f2bf(t.y); s.z = f2bf(t.z); s.w = f2bf(t.w);
    return s;
}

// Native non-returning LDS float add via inline asm.
// Both atomicAdd(float*) AND unsafeAtomicAdd on LDS compile to a
// ds_read+ds_cmpst CAS retry loop on gfx950 (IEEE denormal mode gates the
// native fadd selection) -> divergent dependent ~120cy LDS chains -> the
// 342us acc_gather of rounds 1-2 (identical timing both rounds = identical
// codegen). ds_add_f32 is fire-and-forget: no retries, no dependent chain.
// Generic->LDS addr: low 32 bits of the flat pointer (shared aperture has a
// zero low half; same truncation the compiler emits for addrspacecast).
__device__ inline void lds_fadd(float* p, float v) {
    unsigned off = (unsigned)(unsigned long long)p;
    asm volatile("ds_add_f32 %0, %1" : : "v"(off), "v"(v) : "memory");
}

// ------- Fused stage + MFMA-linear, role-split by blockIdx -------
// Stage role: single-pass ILP-8 binning into fixed-capacity bucket regions.
//   gcur[] is ZERO-BASED per-bucket count (memset by host-side hipMemsetAsync);
//   record for bucket b goes to gstage[b*CAP + intra-bucket offset].
// Linear role: MFMA GEMM h = bf16(feat@W^T + b).
__global__ __launch_bounds__(256) void stage_linear(
    const float* __restrict__ feat, const float* __restrict__ W,
    const float* __restrict__ b, unsigned short* __restrict__ h,
    const int* __restrict__ esrc, const int* __restrict__ edst,
    const float* __restrict__ ew, int* __restrict__ gcur,
    int2* __restrict__ gstage, int n_nodes, int n_edges, int nb, int nstage)
{
    __shared__ union {
        struct { unsigned short As[TM * ALD]; unsigned short Ws[OUT_FEATS * ALD]; } lin;
        struct { int cnt[MAX_NB]; int base[MAX_NB]; } st;
    } sm;
    const int tid = threadIdx.x;

    if ((int)blockIdx.x < nstage) {
        // ---------------- stage role (single pass, ILP-8) ----------------
        int* cnt  = sm.st.cnt;
        int* base = sm.st.base;
        for (int i = tid; i < nb; i += 256) cnt[i] = 0;
        __syncthreads();

        const int e0 = blockIdx.x * SE_PER_BLK + tid * 8;
        int dk[8]; int sk[8]; float wk[8]; int bk[8]; int rk[8];
        if (e0 + 7 < n_edges) {
            *((int4*)&dk[0]) = *((const int4*)&edst[e0]);
            *((int4*)&dk[4]) = *((const int4*)&edst[e0 + 4]);
            *((int4*)&sk[0]) = *((const int4*)&esrc[e0]);
            *((int4*)&sk[4]) = *((const int4*)&esrc[e0 + 4]);
            *((float4*)&wk[0]) = *((const float4*)&ew[e0]);
            *((float4*)&wk[4]) = *((const float4*)&ew[e0 + 4]);
#pragma unroll
            for (int i = 0; i < 8; ++i) {
                bk[i] = dk[i] >> BW_LOG;
                rk[i] = atomicAdd(&cnt[bk[i]], 1);
            }
        } else {
#pragma unroll
            for (int i = 0; i < 8; ++i) {
                int e = e0 + i;
                if (e < n_edges) {
                    dk[i] = edst[e]; sk[i] = esrc[e]; wk[i] = ew[e];
                    bk[i] = dk[i] >> BW_LOG;
                    rk[i] = atomicAdd(&cnt[bk[i]], 1);
                } else bk[i] = -1;
            }
        }
        __syncthreads();
        for (int i = tid; i < nb; i += 256) {
            int c = cnt[i];
            base[i] = c ? atomicAdd(&gcur[i], c) : 0;
        }
        __syncthreads();
#pragma unroll
        for (int i = 0; i < 8; ++i) {
            if (bk[i] >= 0) {
                int off = base[bk[i]] + rk[i];
                // overflow clamp: drop (never taken with CAP = 2x mean margin)
                if (off < CAP)
                    gstage[bk[i] * CAP + off] =
                        make_int2(((dk[i] & (BWIDTH - 1)) << 16) | sk[i],
                                  __float_as_int(wk[i]));
            }
        }
    } else {
        // ---------------- MFMA linear role ----------------
        unsigned short* As = sm.lin.As;
        unsigned short* Ws = sm.lin.Ws;
        const int row0 = ((int)blockIdx.x - nstage) * TM;

        {   // stage W rows -> bf16 LDS
            const int c  = tid & 63;
            const int kb = (tid >> 6) * 32;
            const float4* wrow = (const float4*)(W + (size_t)c * IN_FEATS + kb);
#pragma unroll
            for (int i = 0; i < 8; ++i)
                *((ushort4*)&Ws[c * ALD + kb + i * 4]) = cvt4(wrow[i]);
        }
        {   // stage feat tile -> bf16 LDS
#pragma unroll
            for (int i = 0; i < 8; ++i) {
                int flat = i * 256 + tid;
                int r  = flat >> 5;
                int kc = flat & 31;
                int gr = row0 + r;
                float4 t = (gr < n_nodes)
                    ? ((const float4*)(feat + (size_t)gr * IN_FEATS))[kc]
                    : make_float4(0.f, 0.f, 0.f, 0.f);
                *((ushort4*)&As[r * ALD + kc * 4]) = cvt4(t);
            }
        }
        __syncthreads();

        const int w    = tid >> 6;
        const int lane = tid & 63;
        const int m    = lane & 15;
        const int quad = lane >> 4;
        const int koff = quad * 8;

        f32x4 acc[4];
#pragma unroll
        for (int t = 0; t < 4; ++t) acc[t] = (f32x4){0.f, 0.f, 0.f, 0.f};

#pragma unroll
        for (int chunk = 0; chunk < 4; ++chunk) {
            const int kc = chunk * 32 + koff;
            bf16x8 a = *((const bf16x8*)&As[(w * 16 + m) * ALD + kc]);
#pragma unroll
            for (int t = 0; t < 4; ++t) {
                bf16x8 bfr = *((const bf16x8*)&Ws[(t * 16 + m) * ALD + kc]);
                acc[t] = __builtin_amdgcn_mfma_f32_16x16x32_bf16(a, bfr, acc[t], 0, 0, 0);
            }
        }

#pragma unroll
        for (int t = 0; t < 4; ++t) {
            const int col = t * 16 + m;
            const float bias = b[col];
#pragma unroll
            for (int i = 0; i < 4; ++i) {
                int r = row0 + w * 16 + quad * 4 + i;
                if (r < n_nodes)
                    h[(size_t)r * OUT_FEATS + col] = f2bf(acc[t][i] + bias);
            }
        }
    }
}

// ------- Direct-accumulate gather: one block per bucket, 512 threads -------
// Each 16-lane group owns one UNSORTED record end-to-end and ds_add_f32's into
// a feature-major f32 accumulator tile acc[f][nl] (pad 65). Per-group feature
// permutation l4p = (l4 + 4*grp)&15 makes the 4 groups of a wave write
// mostly-disjoint addresses in every instruction slot; gather coalescing
// unchanged (still 16 consecutive uint2 per group).
__global__ __launch_bounds__(512) void acc_gather(
    const unsigned short* __restrict__ h, const int* __restrict__ gcnt,
    const int2* __restrict__ gstage, float* __restrict__ out, int n_nodes)
{
    __shared__ float acc[OUT_FEATS * APAD];   // 16.6 KB, [feat][node]
    const int tid = threadIdx.x;
    const int b   = blockIdx.x;
    const int s0  = b * CAP;
    const int m   = min(gcnt[b], CAP);

    for (int i = tid; i < OUT_FEATS * APAD; i += 512) acc[i] = 0.f;
    __syncthreads();

    const int grp = tid >> 4;                 // 32 groups of 16 lanes
    const int l4p = ((tid & 15) + ((grp & 3) << 2)) & 15;  // permuted feat slot
    const uint2* h64 = (const uint2*)h;

    int i = grp;
    for (; i + 96 < m; i += 128) {     // ILP-4: 4 independent record chains
        int2 r0 = gstage[s0 + i];
        int2 r1 = gstage[s0 + i + 32];
        int2 r2 = gstage[s0 + i + 64];
        int2 r3 = gstage[s0 + i + 96];
        uint2 v0 = h64[(size_t)(r0.x & 0xFFFF) * 16 + l4p];
        uint2 v1 = h64[(size_t)(r1.x & 0xFFFF) * 16 + l4p];
        uint2 v2 = h64[(size_t)(r2.x & 0xFFFF) * 16 + l4p];
        uint2 v3 = h64[(size_t)(r3.x & 0xFFFF) * 16 + l4p];
        {
            float w = __int_as_float(r0.y);
            float* ap = &acc[(l4p * 4) * APAD + ((r0.x >> 16) & 63)];
            lds_fadd(ap,            w * bf2f_lo(v0.x));
            lds_fadd(ap +     APAD, w * bf2f_hi(v0.x));
            lds_fadd(ap + 2 * APAD, w * bf2f_lo(v0.y));
            lds_fadd(ap + 3 * APAD, w * bf2f_hi(v0.y));
        }
        {
            float w = __int_as_float(r1.y);
            float* ap = &acc[(l4p * 4) * APAD + ((r1.x >> 16) & 63)];
            lds_fadd(ap,            w * bf2f_lo(v1.x));
            lds_fadd(ap +     APAD, w * bf2f_hi(v1.x));
            lds_fadd(ap + 2 * APAD, w * bf2f_lo(v1.y));
            lds_fadd(ap + 3 * APAD, w * bf2f_hi(v1.y));
        }
        {
            float w = __int_as_float(r2.y);
            float* ap = &acc[(l4p * 4) * APAD + ((r2.x >> 16) & 63)];
            lds_fadd(ap,            w * bf2f_lo(v2.x));
            lds_fadd(ap +     APAD, w * bf2f_hi(v2.x));
            lds_fadd(ap + 2 * APAD, w * bf2f_lo(v2.y));
            lds_fadd(ap + 3 * APAD, w * bf2f_hi(v2.y));
        }
        {
            float w = __int_as_float(r3.y);
            float* ap = &acc[(l4p * 4) * APAD + ((r3.x >> 16) & 63)];
            lds_fadd(ap,            w * bf2f_lo(v3.x));
            lds_fadd(ap +     APAD, w * bf2f_hi(v3.x));
            lds_fadd(ap + 2 * APAD, w * bf2f_lo(v3.y));
            lds_fadd(ap + 3 * APAD, w * bf2f_hi(v3.y));
        }
    }
    for (; i < m; i += 32) {           // tail
        int2 r = gstage[s0 + i];
        uint2 v = h64[(size_t)(r.x & 0xFFFF) * 16 + l4p];
        float w = __int_as_float(r.y);
        float* ap = &acc[(l4p * 4) * APAD + ((r.x >> 16) & 63)];
        lds_fadd(ap,            w * bf2f_lo(v.x));
        lds_fadd(ap +     APAD, w * bf2f_hi(v.x));
        lds_fadd(ap + 2 * APAD, w * bf2f_lo(v.y));
        lds_fadd(ap + 3 * APAD, w * bf2f_hi(v.y));
    }
    // Drain asm-issued ds_add_f32 ops the compiler can't see, then barrier.
    asm volatile("s_waitcnt lgkmcnt(0)" ::: "memory");
    __syncthreads();

    // ---- write out: thread -> (node row, 8 feats); transpose via 8 scalar
    // LDS reads (bank = (c0+k+row)%32, 2-way uniform -> free), then 2x float4.
    const int row  = tid >> 3;         // node 0..63
    const int c0   = (tid & 7) * 8;    // feat base
    const int node = b * BWIDTH + row;
    if (node < n_nodes) {
        float o[8];
#pragma unroll
        for (int k = 0; k < 8; ++k) o[k] = acc[(c0 + k) * APAD + row];
        float* dst = &out[(size_t)node * OUT_FEATS + c0];
        *((float4*)dst)       = make_float4(o[0], o[1], o[2], o[3]);
        *((float4*)(dst + 4)) = make_float4(o[4], o[5], o[6], o[7]);
    }
}

// ------- Fallback atomic scatter -------
__global__ __launch_bounds__(256) void scatter_kernel(
    const unsigned short* __restrict__ h, const int* __restrict__ esrc,
    const int* __restrict__ edst, const float* __restrict__ ew,
    float* __restrict__ out, int n_edges)
{
    const int lane = threadIdx.x & 63;
    const int wave = threadIdx.x >> 6;
    const int stride = gridDim.x * 4;
    for (int e = blockIdx.x * 4 + wave; e < n_edges; e += stride) {
        const int s = esrc[e];
        const int d = edst[e];
        const float w = ew[e];
        atomicAdd(out + (size_t)d * OUT_FEATS + lane,
                  bf2f_lo((unsigned)h[(size_t)s * OUT_FEATS + lane]) * w);
    }
}

extern "C" void kernel_launch(void* const* d_in, const int* in_sizes, int n_in,
                              void* d_out, int out_size, void* d_ws, size_t ws_size,
                              hipStream_t stream) {
    const float* feat = (const float*)d_in[0];
    const int*   esrc = (const int*)d_in[1];
    const int*   edst = (const int*)d_in[2];
    const float* ew   = (const float*)d_in[3];
    const float* W    = (const float*)d_in[4];
    const float* b    = (const float*)d_in[5];
    float* out = (float*)d_out;

    const int n_nodes = in_sizes[0] / IN_FEATS;  // 50000
    const int n_edges = in_sizes[1];             // 800000
    const int nb = (n_nodes + BWIDTH - 1) >> BW_LOG;  // 782
    const int nlin = (n_nodes + TM - 1) / TM;         // 782
    const int nstage = (n_edges + SE_PER_BLK - 1) / SE_PER_BLK;  // 391

    // ws: h(bf16 n*64) | gcur(nb) | gstage(nb*CAP int2)
    char* wsb = (char*)d_ws;
    unsigned short* h = (unsigned short*)wsb;
    size_t off_gcur  = (((size_t)n_nodes * OUT_FEATS * sizeof(unsigned short)) + 15) & ~(size_t)15;
    size_t sz_gcur   = (((size_t)nb * sizeof(int)) + 15) & ~(size_t)15;
    size_t off_stage = off_gcur + sz_gcur;
    size_t needed    = off_stage + (size_t)nb * CAP * sizeof(int2);

    // statistical safety: mean bucket load * 1.5 + slack must fit CAP
    bool binnable = (nb <= MAX_NB) && (n_nodes < 65536) &&
                    ((size_t)n_edges / (size_t)nb * 3 / 2 + 300 <= CAP);

    if (ws_size >= needed && binnable) {
        int*  gcur   = (int*)(wsb + off_gcur);
        int2* gstage = (int2*)(wsb + off_stage);
        hipMemsetAsync(gcur, 0, (size_t)nb * sizeof(int), stream);
        stage_linear<<<nstage + nlin, 256, 0, stream>>>(
            feat, W, b, h, esrc, edst, ew, gcur, gstage,
            n_nodes, n_edges, nb, nstage);
        acc_gather<<<nb, 512, 0, stream>>>(h, gcur, gstage, out, n_nodes);
    } else {
        stage_linear<<<nlin, 256, 0, stream>>>(
            feat, W, b, h, esrc, edst, ew, nullptr, nullptr,
            n_nodes, n_edges, nb, 0);
        hipMemsetAsync(d_out, 0, (size_t)out_size * sizeof(float), stream);
        scatter_kernel<<<8192, 256, 0, stream>>>(h, esrc, edst, ew, out, n_edges);
    }
}

// Round 4
// 130.093 us; speedup vs baseline: 3.4514x; 3.4514x over previous
//
#include <hip/hip_runtime.h>

#define IN_FEATS 128
#define OUT_FEATS 64
#define TM 64              // rows per linear block
#define ALD 136            // bf16 LDS leading dim
#define BW_LOG 6           // bucket width = 64 nodes
#define BWIDTH 64
#define MAX_NB 1024
#define SE_PER_BLK 2048    // edges per stage block (256 thr x 8, single pass)
#define CAP 2048           // fixed records per bucket region (mean ~1023, max ~1140)
#define MAXR 4             // CAP / 512 records held in registers per thread

typedef short bf16x8 __attribute__((ext_vector_type(8)));
typedef float f32x4 __attribute__((ext_vector_type(4)));

__device__ inline unsigned short f2bf(float f) {   // RTNE fp32 -> bf16
    unsigned u = __float_as_uint(f);
    u += 0x7FFFu + ((u >> 16) & 1u);
    return (unsigned short)(u >> 16);
}
__device__ inline float bf2f_lo(unsigned v) { return __uint_as_float(v << 16); }
__device__ inline float bf2f_hi(unsigned v) { return __uint_as_float(v & 0xFFFF0000u); }
__device__ inline ushort4 cvt4(float4 t) {
    ushort4 s; s.x = f2bf(t.x); s.y = f2bf(t.y); s.z = f2bf(t.z); s.w = f2bf(t.w);
    return s;
}

// ------- Fused stage + MFMA-linear, role-split by blockIdx -------
// Stage role: single-pass ILP-8 binning into fixed-capacity bucket regions.
//   gcur[] is ZERO-BASED per-bucket count (memset by host-side hipMemsetAsync);
//   record for bucket b goes to gstage[b*CAP + intra-bucket offset].
// Linear role: MFMA GEMM h = bf16(feat@W^T + b).
__global__ __launch_bounds__(256) void stage_linear(
    const float* __restrict__ feat, const float* __restrict__ W,
    const float* __restrict__ b, unsigned short* __restrict__ h,
    const int* __restrict__ esrc, const int* __restrict__ edst,
    const float* __restrict__ ew, int* __restrict__ gcur,
    int2* __restrict__ gstage, int n_nodes, int n_edges, int nb, int nstage)
{
    __shared__ union {
        struct { unsigned short As[TM * ALD]; unsigned short Ws[OUT_FEATS * ALD]; } lin;
        struct { int cnt[MAX_NB]; int base[MAX_NB]; } st;
    } sm;
    const int tid = threadIdx.x;

    if ((int)blockIdx.x < nstage) {
        // ---------------- stage role (single pass, ILP-8) ----------------
        int* cnt  = sm.st.cnt;
        int* base = sm.st.base;
        for (int i = tid; i < nb; i += 256) cnt[i] = 0;
        __syncthreads();

        const int e0 = blockIdx.x * SE_PER_BLK + tid * 8;
        int dk[8]; int sk[8]; float wk[8]; int bk[8]; int rk[8];
        if (e0 + 7 < n_edges) {
            *((int4*)&dk[0]) = *((const int4*)&edst[e0]);
            *((int4*)&dk[4]) = *((const int4*)&edst[e0 + 4]);
            *((int4*)&sk[0]) = *((const int4*)&esrc[e0]);
            *((int4*)&sk[4]) = *((const int4*)&esrc[e0 + 4]);
            *((float4*)&wk[0]) = *((const float4*)&ew[e0]);
            *((float4*)&wk[4]) = *((const float4*)&ew[e0 + 4]);
#pragma unroll
            for (int i = 0; i < 8; ++i) {
                bk[i] = dk[i] >> BW_LOG;
                rk[i] = atomicAdd(&cnt[bk[i]], 1);
            }
        } else {
#pragma unroll
            for (int i = 0; i < 8; ++i) {
                int e = e0 + i;
                if (e < n_edges) {
                    dk[i] = edst[e]; sk[i] = esrc[e]; wk[i] = ew[e];
                    bk[i] = dk[i] >> BW_LOG;
                    rk[i] = atomicAdd(&cnt[bk[i]], 1);
                } else bk[i] = -1;
            }
        }
        __syncthreads();
        for (int i = tid; i < nb; i += 256) {
            int c = cnt[i];
            base[i] = c ? atomicAdd(&gcur[i], c) : 0;
        }
        __syncthreads();
#pragma unroll
        for (int i = 0; i < 8; ++i) {
            if (bk[i] >= 0) {
                int off = base[bk[i]] + rk[i];
                // overflow clamp: drop (never taken with CAP = 2x mean margin)
                if (off < CAP)
                    gstage[bk[i] * CAP + off] =
                        make_int2(((dk[i] & (BWIDTH - 1)) << 16) | sk[i],
                                  __float_as_int(wk[i]));
            }
        }
    } else {
        // ---------------- MFMA linear role ----------------
        unsigned short* As = sm.lin.As;
        unsigned short* Ws = sm.lin.Ws;
        const int row0 = ((int)blockIdx.x - nstage) * TM;

        {   // stage W rows -> bf16 LDS
            const int c  = tid & 63;
            const int kb = (tid >> 6) * 32;
            const float4* wrow = (const float4*)(W + (size_t)c * IN_FEATS + kb);
#pragma unroll
            for (int i = 0; i < 8; ++i)
                *((ushort4*)&Ws[c * ALD + kb + i * 4]) = cvt4(wrow[i]);
        }
        {   // stage feat tile -> bf16 LDS
#pragma unroll
            for (int i = 0; i < 8; ++i) {
                int flat = i * 256 + tid;
                int r  = flat >> 5;
                int kc = flat & 31;
                int gr = row0 + r;
                float4 t = (gr < n_nodes)
                    ? ((const float4*)(feat + (size_t)gr * IN_FEATS))[kc]
                    : make_float4(0.f, 0.f, 0.f, 0.f);
                *((ushort4*)&As[r * ALD + kc * 4]) = cvt4(t);
            }
        }
        __syncthreads();

        const int w    = tid >> 6;
        const int lane = tid & 63;
        const int m    = lane & 15;
        const int quad = lane >> 4;
        const int koff = quad * 8;

        f32x4 acc[4];
#pragma unroll
        for (int t = 0; t < 4; ++t) acc[t] = (f32x4){0.f, 0.f, 0.f, 0.f};

#pragma unroll
        for (int chunk = 0; chunk < 4; ++chunk) {
            const int kc = chunk * 32 + koff;
            bf16x8 a = *((const bf16x8*)&As[(w * 16 + m) * ALD + kc]);
#pragma unroll
            for (int t = 0; t < 4; ++t) {
                bf16x8 bfr = *((const bf16x8*)&Ws[(t * 16 + m) * ALD + kc]);
                acc[t] = __builtin_amdgcn_mfma_f32_16x16x32_bf16(a, bfr, acc[t], 0, 0, 0);
            }
        }

#pragma unroll
        for (int t = 0; t < 4; ++t) {
            const int col = t * 16 + m;
            const float bias = b[col];
#pragma unroll
            for (int i = 0; i < 4; ++i) {
                int r = row0 + w * 16 + quad * 4 + i;
                if (r < n_nodes)
                    h[(size_t)r * OUT_FEATS + col] = f2bf(acc[t][i] + bias);
            }
        }
    }
}

// ------- Fused sort + gather: one block per bucket, 512 threads -------
// Round-0 proven structure (counting sort -> ownership gather), with ONE
// delta: records are held in REGISTERS (<=MAXR per thread, static unroll)
// between histogram and scatter, deleting the recs[] LDS array and its
// write+read pass (33KB -> 17KB LDS). Everything else byte-identical.
__global__ __launch_bounds__(512) void sort_gather(
    const unsigned short* __restrict__ h, const int* __restrict__ gcnt,
    const int2* __restrict__ gstage, float* __restrict__ out, int n_nodes)
{
    __shared__ int2 srec[CAP];
    __shared__ int cnt[BWIDTH];
    __shared__ int cur0[BWIDTH];
    __shared__ int cur[BWIDTH];
    const int tid = threadIdx.x;
    const int b   = blockIdx.x;
    const int s0  = b * CAP;
    const int m   = min(gcnt[b], CAP);

    if (tid < BWIDTH) cnt[tid] = 0;
    __syncthreads();

    int2 rl[MAXR];
#pragma unroll
    for (int k = 0; k < MAXR; ++k) {
        int i = tid + k * 512;
        if (i < m) {
            rl[k] = gstage[s0 + i];
            atomicAdd(&cnt[(rl[k].x >> 16) & 63], 1);
        }
    }
    __syncthreads();

    if (tid < 64) {   // wave 0: exclusive scan of 64 counters
        int v = cnt[tid];
        int inc = v;
        for (int o = 1; o < 64; o <<= 1) {
            int t = __shfl_up(inc, o, 64);
            if (tid >= o) inc += t;
        }
        int excl = inc - v;
        cur0[tid] = excl;
        cur[tid]  = excl;
    }
    __syncthreads();

#pragma unroll
    for (int k = 0; k < MAXR; ++k) {
        int i = tid + k * 512;
        if (i < m) {
            int pos = atomicAdd(&cur[(rl[k].x >> 16) & 63], 1);
            srec[pos] = rl[k];
        }
    }
    __syncthreads();

    // ---- gather from LDS ----
    const int lane = tid & 63;
    const int wv   = tid >> 6;          // 8 waves
    const int g    = lane >> 4;         // node group within wave (0..3)
    const int f4   = lane & 15;         // uint2 index: feats 4*f4..4*f4+3
    const uint2* h64 = (const uint2*)h;

#pragma unroll
    for (int it = 0; it < 2; ++it) {
        const int nl   = wv * 8 + it * 4 + g;   // local node 0..63
        const int node = b * BWIDTH + nl;
        const int st   = cur0[nl];
        const int len  = cnt[nl];
        int omax = len;
        omax = max(omax, __shfl_xor(omax, 16, 64));
        omax = max(omax, __shfl_xor(omax, 32, 64));

        float a0 = 0.f, a1 = 0.f, a2 = 0.f, a3 = 0.f;
        for (int u = 0; u < omax; u += 8) {
            int2 r[8]; uint2 hv[8];
#pragma unroll
            for (int k = 0; k < 8; ++k) {
                int uk = u + k;
                r[k] = srec[(uk < len) ? (st + uk) : 0];
            }
#pragma unroll
            for (int k = 0; k < 8; ++k)
                hv[k] = h64[(size_t)(r[k].x & 0xFFFF) * 16 + f4];
#pragma unroll
            for (int k = 0; k < 8; ++k) {
                float w = (u + k < len) ? __int_as_float(r[k].y) : 0.f;
                a0 += w * bf2f_lo(hv[k].x);
                a1 += w * bf2f_hi(hv[k].x);
                a2 += w * bf2f_lo(hv[k].y);
                a3 += w * bf2f_hi(hv[k].y);
            }
        }
        if (node < n_nodes) {
            float4 o; o.x = a0; o.y = a1; o.z = a2; o.w = a3;
            *((float4*)&out[(size_t)node * OUT_FEATS + f4 * 4]) = o;
        }
    }
}

// ------- Fallback atomic scatter -------
__global__ __launch_bounds__(256) void scatter_kernel(
    const unsigned short* __restrict__ h, const int* __restrict__ esrc,
    const int* __restrict__ edst, const float* __restrict__ ew,
    float* __restrict__ out, int n_edges)
{
    const int lane = threadIdx.x & 63;
    const int wave = threadIdx.x >> 6;
    const int stride = gridDim.x * 4;
    for (int e = blockIdx.x * 4 + wave; e < n_edges; e += stride) {
        const int s = esrc[e];
        const int d = edst[e];
        const float w = ew[e];
        atomicAdd(out + (size_t)d * OUT_FEATS + lane,
                  bf2f_lo((unsigned)h[(size_t)s * OUT_FEATS + lane]) * w);
    }
}

extern "C" void kernel_launch(void* const* d_in, const int* in_sizes, int n_in,
                              void* d_out, int out_size, void* d_ws, size_t ws_size,
                              hipStream_t stream) {
    const float* feat = (const float*)d_in[0];
    const int*   esrc = (const int*)d_in[1];
    const int*   edst = (const int*)d_in[2];
    const float* ew   = (const float*)d_in[3];
    const float* W    = (const float*)d_in[4];
    const float* b    = (const float*)d_in[5];
    float* out = (float*)d_out;

    const int n_nodes = in_sizes[0] / IN_FEATS;  // 50000
    const int n_edges = in_sizes[1];             // 800000
    const int nb = (n_nodes + BWIDTH - 1) >> BW_LOG;  // 782
    const int nlin = (n_nodes + TM - 1) / TM;         // 782
    const int nstage = (n_edges + SE_PER_BLK - 1) / SE_PER_BLK;  // 391

    // ws: h(bf16 n*64) | gcur(nb) | gstage(nb*CAP int2)
    char* wsb = (char*)d_ws;
    unsigned short* h = (unsigned short*)wsb;
    size_t off_gcur  = (((size_t)n_nodes * OUT_FEATS * sizeof(unsigned short)) + 15) & ~(size_t)15;
    size_t sz_gcur   = (((size_t)nb * sizeof(int)) + 15) & ~(size_t)15;
    size_t off_stage = off_gcur + sz_gcur;
    size_t needed    = off_stage + (size_t)nb * CAP * sizeof(int2);

    // statistical safety: mean bucket load * 1.5 + slack must fit CAP
    bool binnable = (nb <= MAX_NB) && (n_nodes < 65536) &&
                    ((size_t)n_edges / (size_t)nb * 3 / 2 + 300 <= CAP);

    if (ws_size >= needed && binnable) {
        int*  gcur   = (int*)(wsb + off_gcur);
        int2* gstage = (int2*)(wsb + off_stage);
        hipMemsetAsync(gcur, 0, (size_t)nb * sizeof(int), stream);
        stage_linear<<<nstage + nlin, 256, 0, stream>>>(
            feat, W, b, h, esrc, edst, ew, gcur, gstage,
            n_nodes, n_edges, nb, nstage);
        sort_gather<<<nb, 512, 0, stream>>>(h, gcur, gstage, out, n_nodes);
    } else {
        stage_linear<<<nlin, 256, 0, stream>>>(
            feat, W, b, h, esrc, edst, ew, nullptr, nullptr,
            n_nodes, n_edges, nb, 0);
        hipMemsetAsync(d_out, 0, (size_t)out_size * sizeof(float), stream);
        scatter_kernel<<<8192, 256, 0, stream>>>(h, esrc, edst, ew, out, n_edges);
    }
}

// Round 5
// 124.981 us; speedup vs baseline: 3.5925x; 1.0409x over previous
//
#include <hip/hip_runtime.h>

#define IN_FEATS 128
#define OUT_FEATS 64
#define TM 64              // rows per linear block
#define ALD 136            // bf16 LDS leading dim
#define BW_LOG 6           // bucket width = 64 nodes
#define BWIDTH 64
#define MAX_NB 1024
#define SE_PER_BLK 2048    // edges per stage block (256 thr x 8, single pass)
#define CAP 2048           // fixed records per bucket region (mean ~1023, max ~1140)
#define MAXR 4             // CAP / 512 records held in registers per thread

typedef short bf16x8 __attribute__((ext_vector_type(8)));
typedef float f32x4 __attribute__((ext_vector_type(4)));

__device__ inline unsigned short f2bf(float f) {   // RTNE fp32 -> bf16
    unsigned u = __float_as_uint(f);
    u += 0x7FFFu + ((u >> 16) & 1u);
    return (unsigned short)(u >> 16);
}
__device__ inline float bf2f_lo(unsigned v) { return __uint_as_float(v << 16); }
__device__ inline float bf2f_hi(unsigned v) { return __uint_as_float(v & 0xFFFF0000u); }
__device__ inline ushort4 cvt4(float4 t) {
    ushort4 s; s.x = f2bf(t.x); s.y = f2bf(t.y); s.z = f2bf(t.z); s.w = f2bf(t.w);
    return s;
}

// ------- Init: zero per-bucket counts -------
// NOTE: hipMemsetAsync(gcur, 3KB) becomes a rocclr fillBuffer dispatch that
// showed 44us in rocprof (round 4) -- a plain 1-block kernel is cheaper.
__global__ __launch_bounds__(256) void init_cursors(int* __restrict__ gcur, int nb)
{
    for (int i = threadIdx.x; i < nb; i += 256) gcur[i] = 0;
}

// ------- Fused stage + MFMA-linear, role-split by blockIdx -------
// Stage role: single-pass ILP-8 binning into fixed-capacity bucket regions.
//   gcur[] is ZERO-BASED per-bucket count; record for bucket b goes to
//   gstage[b*CAP + intra-bucket offset].
// Linear role: MFMA GEMM h = bf16(feat@W^T + b).
__global__ __launch_bounds__(256) void stage_linear(
    const float* __restrict__ feat, const float* __restrict__ W,
    const float* __restrict__ b, unsigned short* __restrict__ h,
    const int* __restrict__ esrc, const int* __restrict__ edst,
    const float* __restrict__ ew, int* __restrict__ gcur,
    int2* __restrict__ gstage, int n_nodes, int n_edges, int nb, int nstage)
{
    __shared__ union {
        struct { unsigned short As[TM * ALD]; unsigned short Ws[OUT_FEATS * ALD]; } lin;
        struct { int cnt[MAX_NB]; int base[MAX_NB]; } st;
    } sm;
    const int tid = threadIdx.x;

    if ((int)blockIdx.x < nstage) {
        // ---------------- stage role (single pass, ILP-8) ----------------
        int* cnt  = sm.st.cnt;
        int* base = sm.st.base;
        for (int i = tid; i < nb; i += 256) cnt[i] = 0;
        __syncthreads();

        const int e0 = blockIdx.x * SE_PER_BLK + tid * 8;
        int dk[8]; int sk[8]; float wk[8]; int bk[8]; int rk[8];
        if (e0 + 7 < n_edges) {
            *((int4*)&dk[0]) = *((const int4*)&edst[e0]);
            *((int4*)&dk[4]) = *((const int4*)&edst[e0 + 4]);
            *((int4*)&sk[0]) = *((const int4*)&esrc[e0]);
            *((int4*)&sk[4]) = *((const int4*)&esrc[e0 + 4]);
            *((float4*)&wk[0]) = *((const float4*)&ew[e0]);
            *((float4*)&wk[4]) = *((const float4*)&ew[e0 + 4]);
#pragma unroll
            for (int i = 0; i < 8; ++i) {
                bk[i] = dk[i] >> BW_LOG;
                rk[i] = atomicAdd(&cnt[bk[i]], 1);
            }
        } else {
#pragma unroll
            for (int i = 0; i < 8; ++i) {
                int e = e0 + i;
                if (e < n_edges) {
                    dk[i] = edst[e]; sk[i] = esrc[e]; wk[i] = ew[e];
                    bk[i] = dk[i] >> BW_LOG;
                    rk[i] = atomicAdd(&cnt[bk[i]], 1);
                } else bk[i] = -1;
            }
        }
        __syncthreads();
        for (int i = tid; i < nb; i += 256) {
            int c = cnt[i];
            base[i] = c ? atomicAdd(&gcur[i], c) : 0;
        }
        __syncthreads();
#pragma unroll
        for (int i = 0; i < 8; ++i) {
            if (bk[i] >= 0) {
                int off = base[bk[i]] + rk[i];
                // overflow clamp: drop (never taken with CAP = 2x mean margin)
                if (off < CAP)
                    gstage[bk[i] * CAP + off] =
                        make_int2(((dk[i] & (BWIDTH - 1)) << 16) | sk[i],
                                  __float_as_int(wk[i]));
            }
        }
    } else {
        // ---------------- MFMA linear role ----------------
        unsigned short* As = sm.lin.As;
        unsigned short* Ws = sm.lin.Ws;
        const int row0 = ((int)blockIdx.x - nstage) * TM;

        {   // stage W rows -> bf16 LDS
            const int c  = tid & 63;
            const int kb = (tid >> 6) * 32;
            const float4* wrow = (const float4*)(W + (size_t)c * IN_FEATS + kb);
#pragma unroll
            for (int i = 0; i < 8; ++i)
                *((ushort4*)&Ws[c * ALD + kb + i * 4]) = cvt4(wrow[i]);
        }
        {   // stage feat tile -> bf16 LDS
#pragma unroll
            for (int i = 0; i < 8; ++i) {
                int flat = i * 256 + tid;
                int r  = flat >> 5;
                int kc = flat & 31;
                int gr = row0 + r;
                float4 t = (gr < n_nodes)
                    ? ((const float4*)(feat + (size_t)gr * IN_FEATS))[kc]
                    : make_float4(0.f, 0.f, 0.f, 0.f);
                *((ushort4*)&As[r * ALD + kc * 4]) = cvt4(t);
            }
        }
        __syncthreads();

        const int w    = tid >> 6;
        const int lane = tid & 63;
        const int m    = lane & 15;
        const int quad = lane >> 4;
        const int koff = quad * 8;

        f32x4 acc[4];
#pragma unroll
        for (int t = 0; t < 4; ++t) acc[t] = (f32x4){0.f, 0.f, 0.f, 0.f};

#pragma unroll
        for (int chunk = 0; chunk < 4; ++chunk) {
            const int kc = chunk * 32 + koff;
            bf16x8 a = *((const bf16x8*)&As[(w * 16 + m) * ALD + kc]);
#pragma unroll
            for (int t = 0; t < 4; ++t) {
                bf16x8 bfr = *((const bf16x8*)&Ws[(t * 16 + m) * ALD + kc]);
                acc[t] = __builtin_amdgcn_mfma_f32_16x16x32_bf16(a, bfr, acc[t], 0, 0, 0);
            }
        }

#pragma unroll
        for (int t = 0; t < 4; ++t) {
            const int col = t * 16 + m;
            const float bias = b[col];
#pragma unroll
            for (int i = 0; i < 4; ++i) {
                int r = row0 + w * 16 + quad * 4 + i;
                if (r < n_nodes)
                    h[(size_t)r * OUT_FEATS + col] = f2bf(acc[t][i] + bias);
            }
        }
    }
}

// ------- Fused sort + gather: one block per bucket, 512 threads -------
// Counting sort (records held in registers between histogram and scatter),
// then WAVE-PER-NODE exact-length gather: the whole wave processes one node
// at a time, 4 records/iter x 16 feat-lanes, loop bound = exact len
// (wave-uniform). Replaces the omax-padded scheme whose wave-max bound
// issued ~35-40% dead srec reads / h-gathers / FMAs (omax ~ max of 4
// Poisson(16) ~ 22-24 vs mean 16). Cross-group reduce = 2 shfl_xor per acc.
__global__ __launch_bounds__(512) void sort_gather(
    const unsigned short* __restrict__ h, const int* __restrict__ gcnt,
    const int2* __restrict__ gstage, float* __restrict__ out, int n_nodes)
{
    __shared__ int2 srec[CAP];
    __shared__ int cnt[BWIDTH];
    __shared__ int cur0[BWIDTH];
    __shared__ int cur[BWIDTH];
    const int tid = threadIdx.x;
    const int b   = blockIdx.x;
    const int s0  = b * CAP;
    const int m   = min(gcnt[b], CAP);

    if (tid < BWIDTH) cnt[tid] = 0;
    __syncthreads();

    int2 rl[MAXR];
#pragma unroll
    for (int k = 0; k < MAXR; ++k) {
        int i = tid + k * 512;
        if (i < m) {
            rl[k] = gstage[s0 + i];
            atomicAdd(&cnt[(rl[k].x >> 16) & 63], 1);
        }
    }
    __syncthreads();

    if (tid < 64) {   // wave 0: exclusive scan of 64 counters
        int v = cnt[tid];
        int inc = v;
        for (int o = 1; o < 64; o <<= 1) {
            int t = __shfl_up(inc, o, 64);
            if (tid >= o) inc += t;
        }
        int excl = inc - v;
        cur0[tid] = excl;
        cur[tid]  = excl;
    }
    __syncthreads();

#pragma unroll
    for (int k = 0; k < MAXR; ++k) {
        int i = tid + k * 512;
        if (i < m) {
            int pos = atomicAdd(&cur[(rl[k].x >> 16) & 63], 1);
            srec[pos] = rl[k];
        }
    }
    __syncthreads();

    // ---- wave-per-node exact-length gather ----
    const int lane = tid & 63;
    const int wv   = tid >> 6;          // 8 waves, 8 nodes each
    const int g    = lane >> 4;         // record slot within iteration (0..3)
    const int f4   = lane & 15;         // uint2 index: feats 4*f4..4*f4+3
    const uint2* h64 = (const uint2*)h;

    for (int nl8 = 0; nl8 < 8; ++nl8) {
        const int nl   = wv * 8 + nl8;          // local node (wave-uniform)
        const int node = b * BWIDTH + nl;
        const int st   = cur0[nl];
        const int len  = cnt[nl];               // wave-uniform

        float a0 = 0.f, a1 = 0.f, a2 = 0.f, a3 = 0.f;
        int u = g;
        for (; u + 4 < len; u += 8) {           // unroll-2: two gathers in flight
            int2 r0 = srec[st + u];             // 16-lane broadcast read
            int2 r1 = srec[st + u + 4];
            uint2 v0 = h64[(size_t)(r0.x & 0xFFFF) * 16 + f4];
            uint2 v1 = h64[(size_t)(r1.x & 0xFFFF) * 16 + f4];
            float w0 = __int_as_float(r0.y);
            float w1 = __int_as_float(r1.y);
            a0 += w0 * bf2f_lo(v0.x); a1 += w0 * bf2f_hi(v0.x);
            a2 += w0 * bf2f_lo(v0.y); a3 += w0 * bf2f_hi(v0.y);
            a0 += w1 * bf2f_lo(v1.x); a1 += w1 * bf2f_hi(v1.x);
            a2 += w1 * bf2f_lo(v1.y); a3 += w1 * bf2f_hi(v1.y);
        }
        if (u < len) {                          // tail (<= 1 iter per group)
            int2 r = srec[st + u];
            uint2 v = h64[(size_t)(r.x & 0xFFFF) * 16 + f4];
            float w = __int_as_float(r.y);
            a0 += w * bf2f_lo(v.x); a1 += w * bf2f_hi(v.x);
            a2 += w * bf2f_lo(v.y); a3 += w * bf2f_hi(v.y);
        }
        // reduce the 4 record-groups onto every lane (xor16 then xor32)
        a0 += __shfl_xor(a0, 16, 64); a0 += __shfl_xor(a0, 32, 64);
        a1 += __shfl_xor(a1, 16, 64); a1 += __shfl_xor(a1, 32, 64);
        a2 += __shfl_xor(a2, 16, 64); a2 += __shfl_xor(a2, 32, 64);
        a3 += __shfl_xor(a3, 16, 64); a3 += __shfl_xor(a3, 32, 64);

        if (g == 0 && node < n_nodes) {
            float4 o; o.x = a0; o.y = a1; o.z = a2; o.w = a3;
            *((float4*)&out[(size_t)node * OUT_FEATS + f4 * 4]) = o;
        }
    }
}

// ------- Fallback atomic scatter -------
__global__ __launch_bounds__(256) void scatter_kernel(
    const unsigned short* __restrict__ h, const int* __restrict__ esrc,
    const int* __restrict__ edst, const float* __restrict__ ew,
    float* __restrict__ out, int n_edges)
{
    const int lane = threadIdx.x & 63;
    const int wave = threadIdx.x >> 6;
    const int stride = gridDim.x * 4;
    for (int e = blockIdx.x * 4 + wave; e < n_edges; e += stride) {
        const int s = esrc[e];
        const int d = edst[e];
        const float w = ew[e];
        atomicAdd(out + (size_t)d * OUT_FEATS + lane,
                  bf2f_lo((unsigned)h[(size_t)s * OUT_FEATS + lane]) * w);
    }
}

extern "C" void kernel_launch(void* const* d_in, const int* in_sizes, int n_in,
                              void* d_out, int out_size, void* d_ws, size_t ws_size,
                              hipStream_t stream) {
    const float* feat = (const float*)d_in[0];
    const int*   esrc = (const int*)d_in[1];
    const int*   edst = (const int*)d_in[2];
    const float* ew   = (const float*)d_in[3];
    const float* W    = (const float*)d_in[4];
    const float* b    = (const float*)d_in[5];
    float* out = (float*)d_out;

    const int n_nodes = in_sizes[0] / IN_FEATS;  // 50000
    const int n_edges = in_sizes[1];             // 800000
    const int nb = (n_nodes + BWIDTH - 1) >> BW_LOG;  // 782
    const int nlin = (n_nodes + TM - 1) / TM;         // 782
    const int nstage = (n_edges + SE_PER_BLK - 1) / SE_PER_BLK;  // 391

    // ws: h(bf16 n*64) | gcur(nb) | gstage(nb*CAP int2)
    char* wsb = (char*)d_ws;
    unsigned short* h = (unsigned short*)wsb;
    size_t off_gcur  = (((size_t)n_nodes * OUT_FEATS * sizeof(unsigned short)) + 15) & ~(size_t)15;
    size_t sz_gcur   = (((size_t)nb * sizeof(int)) + 15) & ~(size_t)15;
    size_t off_stage = off_gcur + sz_gcur;
    size_t needed    = off_stage + (size_t)nb * CAP * sizeof(int2);

    // statistical safety: mean bucket load * 1.5 + slack must fit CAP
    bool binnable = (nb <= MAX_NB) && (n_nodes < 65536) &&
                    ((size_t)n_edges / (size_t)nb * 3 / 2 + 300 <= CAP);

    if (ws_size >= needed && binnable) {
        int*  gcur   = (int*)(wsb + off_gcur);
        int2* gstage = (int2*)(wsb + off_stage);
        init_cursors<<<1, 256, 0, stream>>>(gcur, nb);
        stage_linear<<<nstage + nlin, 256, 0, stream>>>(
            feat, W, b, h, esrc, edst, ew, gcur, gstage,
            n_nodes, n_edges, nb, nstage);
        sort_gather<<<nb, 512, 0, stream>>>(h, gcur, gstage, out, n_nodes);
    } else {
        stage_linear<<<nlin, 256, 0, stream>>>(
            feat, W, b, h, esrc, edst, ew, nullptr, nullptr,
            n_nodes, n_edges, nb, 0);
        hipMemsetAsync(d_out, 0, (size_t)out_size * sizeof(float), stream);
        scatter_kernel<<<8192, 256, 0, stream>>>(h, esrc, edst, ew, out, n_edges);
    }
}